// Round 7
// baseline (1137.372 us; speedup 1.0000x reference)
//
#include <hip/hip_runtime.h>
#include <hip/hip_bf16.h>

// Fused Comm_OUT pipeline — Round-13: WAVE-AUTONOMOUS redesign.
// Six rounds showed the 8-wave barrier'd decomposition is structurally
// latency-bound (~70% idle issue): h split across waves forces an
// inter-wave exchange + barrier every GRU step. This version: ONE wave
// owns 32 batch rows end-to-end. Swapped MFMA operands (D = W x h^T;
// operand layouts are symmetric, existing g_wpk packing reused as A)
// put D's row dim on lane&15 so the D->B-operand conversion is a
// same-lane LDS write/read: ZERO barriers in the 20-step loop, only
// intra-wave s_waitcnt lgkmcnt(0) (vmcnt untouched -> loads pipeline).
// h carried in registers as B-frags (bf16); gi in LDS (D-layout,
// r/z packed bf16, n f32 — r3 numerics); Wc/Wmu chained in-wave.
// 256 blocks x 64 threads (1 wave, 32 rows), 1 block/CU (128KB LDS).
// Runtime dtype detection (inputs fp32 or bf16) via g_flag.

typedef __attribute__((ext_vector_type(8))) short bf16x8;   // 8 x bf16
typedef __attribute__((ext_vector_type(4))) float f32x4;    // MFMA acc
typedef __attribute__((ext_vector_type(4))) float f32x4n;   // 16B vec ld/st
typedef __attribute__((ext_vector_type(4))) unsigned short u16x4;  // 8B
typedef __attribute__((ext_vector_type(4))) unsigned int  u32x4;   // 16B

#define MFMA16(a, b, c) __builtin_amdgcn_mfma_f32_16x16x32_bf16((a), (b), (c), 0, 0, 0)
#define LGKM0() asm volatile("s_waitcnt lgkmcnt(0)" ::: "memory")

constexpr int F   = 640;
constexpr int H   = 256;
constexpr int LSTEPS = 20;
constexpr int CO  = 32;
constexpr int RPW = 32;     // rows per wave/block

// packed-weight element offsets inside g_wpk (layout unchanged from r7)
constexpr size_t WHH_E  = 0;
constexpr size_t WIH_E  = 196608;
constexpr size_t WC_E   = 393216;
constexpr size_t WMU_E  = 458752;
constexpr size_t WLIN_E = 466944;
constexpr size_t PK_ELEMS = 630784;

// LDS layout (bytes)
constexpr int LDT  = 264;     // transpose-buffer stride (elems)
constexpr int LDWS = 648;     // hw-slab stride (elems)
constexpr int OFF_TBH   = 0;        // 32*264*2 = 16896   h (persist)
constexpr int OFF_TBY   = 16896;    // 16896              y
constexpr int OFF_TBZ   = 33792;    // 16896              z
constexpr int OFF_HWS   = 16896;    // 41472  phase-1 only, overlaps TBY/TBZ
constexpr int OFF_GI_RZ = 58368;    // 2*16*64*16 = 32768
constexpr int OFF_GI_N  = 91136;    // 32768
constexpr int OFF_PRM1  = 123904;   // 256*2*4 = 2048  (s1, t1') pairs
constexpr int OFF_PRM2  = 125952;   // 2048            (s2, t2)
constexpr int OFF_PRM3  = 128000;   // 2048            (s3, t3f)
constexpr int OFF_PRMN  = 130048;   // 1024            bhh_n
constexpr int SMEM_SZ   = 131072;   // 128 KB -> 1 block/CU

__device__ __align__(16) unsigned short g_wpk[PK_ELEMS];
__device__ int g_flag;     // 1 = inputs are fp32

__device__ __forceinline__ float bf2f(__hip_bfloat16 x) { return __bfloat162float(x); }
__device__ __forceinline__ float bfu(unsigned short s) {
    __hip_bfloat16 h = *reinterpret_cast<__hip_bfloat16*>(&s);
    return __bfloat162float(h);
}
__device__ __forceinline__ unsigned short f2bs(float f) {
    __hip_bfloat16 h = __float2bfloat16(f);
    return *reinterpret_cast<unsigned short*>(&h);
}
__device__ __forceinline__ bf16x8 pk8(size_t eoff) {
    return *reinterpret_cast<const bf16x8*>(g_wpk + eoff);
}
__device__ __forceinline__ float sigm(float x) {
    return 1.0f / (1.0f + __expf(-x));
}
__device__ __forceinline__ unsigned pack2(float lo, float hi) {
    return (unsigned)f2bs(lo) | ((unsigned)f2bs(hi) << 16);
}

template<bool F32>
__device__ __forceinline__ bf16x8 g8(const void* base, size_t off) {
    if constexpr (!F32) {
        return *reinterpret_cast<const bf16x8*>((const __hip_bfloat16*)base + off);
    } else {
        const float* f = (const float*)base + off;
        f32x4n lo = *reinterpret_cast<const f32x4n*>(f);
        f32x4n hi = *reinterpret_cast<const f32x4n*>(f + 4);
        bf16x8 r;
        r[0] = (short)f2bs(lo[0]); r[1] = (short)f2bs(lo[1]);
        r[2] = (short)f2bs(lo[2]); r[3] = (short)f2bs(lo[3]);
        r[4] = (short)f2bs(hi[0]); r[5] = (short)f2bs(hi[1]);
        r[6] = (short)f2bs(hi[2]); r[7] = (short)f2bs(hi[3]);
        return r;
    }
}

template<bool F32>
__device__ __forceinline__ float ld1(const void* base, int i) {
    if constexpr (!F32) return bf2f(((const __hip_bfloat16*)base)[i]);
    else                return ((const float*)base)[i];
}

// ---------------- dtype detect: v1 (uniform[0.5,1.5]) ----------------
__global__ void detect_dtype(const void* v1) {
    const unsigned short* u = (const unsigned short*)v1;
    int f32 = 0;
    for (int i = 0; i < 8; ++i) {
        unsigned short s = u[i];
        __hip_bfloat16 h = *reinterpret_cast<__hip_bfloat16*>(&s);
        float v = __bfloat162float(h);
        if (!(v >= 0.25f && v <= 2.0f)) f32 = 1;
    }
    g_flag = f32;
}

// ---------------- weight pre-pack (unchanged layout) ----------------
__device__ __forceinline__ unsigned short cvt1(const void* p, size_t i, bool f32) {
    if (f32) return f2bs(((const float*)p)[i]);
    return ((const unsigned short*)p)[i];
}

__global__ void prepack(const void* Wlin, const void* Wih, const void* Whh,
                        const void* Wc, const void* Wmu) {
    const bool f32 = (g_flag != 0);
    const int gid = blockIdx.x * 256 + threadIdx.x;
    const void* src;
    size_t dbase;
    int row, col0, ncols;
    if (gid < 24576) {                       // Whh [768,256]
        int idx = gid;
        int lane = idx & 63, j = (idx >> 6) & 1, kk = (idx >> 7) & 7;
        int t2 = idx >> 10, g = t2 % 3, w = t2 / 3;
        row = g * 256 + w * 32 + j * 16 + (lane & 15);
        col0 = kk * 32 + (lane >> 4) * 8;
        ncols = 256; src = Whh; dbase = WHH_E + (size_t)idx * 8;
    } else if (gid < 49152) {                // Wih [768,256]
        int idx = gid - 24576;
        int lane = idx & 63, j = (idx >> 6) & 1, kk = (idx >> 7) & 7;
        int t2 = idx >> 10, g = t2 % 3, w = t2 / 3;
        row = g * 256 + w * 32 + j * 16 + (lane & 15);
        col0 = kk * 32 + (lane >> 4) * 8;
        ncols = 256; src = Wih; dbase = WIH_E + (size_t)idx * 8;
    } else if (gid < 57344) {                // Wc [256,256]
        int idx = gid - 49152;
        int lane = idx & 63, j = (idx >> 6) & 1, kk = (idx >> 7) & 7, w = idx >> 10;
        row = w * 32 + j * 16 + (lane & 15);
        col0 = kk * 32 + (lane >> 4) * 8;
        ncols = 256; src = Wc; dbase = WC_E + (size_t)idx * 8;
    } else if (gid < 58368) {                // Wmu [32,256]
        int idx = gid - 57344;
        int lane = idx & 63, kk = (idx >> 6) & 7, w = idx >> 9;
        row = w * 16 + (lane & 15);
        col0 = kk * 32 + (lane >> 4) * 8;
        ncols = 256; src = Wmu; dbase = WMU_E + (size_t)idx * 8;
    } else if (gid < 78848) {                // Wlin [256,640]
        int idx = gid - 58368;
        int lane = idx & 63, j = (idx >> 6) & 1;
        int t1 = idx >> 7, kk = t1 % 20, w = t1 / 20;
        row = w * 32 + j * 16 + (lane & 15);
        col0 = kk * 32 + (lane >> 4) * 8;
        ncols = 640; src = Wlin; dbase = WLIN_E + (size_t)idx * 8;
    } else {
        return;
    }
    const size_t s0 = (size_t)row * ncols + col0;
    #pragma unroll
    for (int i = 0; i < 8; ++i) g_wpk[dbase + i] = cvt1(src, s0 + i, f32);
}

// ---------------- WAVE-AUTONOMOUS PIPE: 1 wave, 32 rows, 0 loop barriers ----------------
template<bool F32>
__device__ __forceinline__ void wave_pipe(
    const void* hw, const void* blin,
    const void* g1, const void* be1, const void* m1, const void* v1, const void* a1,
    const void* bih, const void* bhh,
    const void* g2, const void* be2, const void* m2, const void* v2, const void* a2,
    const void* bc,
    const void* g3, const void* be3, const void* m3, const void* v3, const void* a3,
    const void* bmu,
    void* out, char* smem)
{
    unsigned short* tbh = (unsigned short*)(smem + OFF_TBH);
    unsigned short* tby = (unsigned short*)(smem + OFF_TBY);
    unsigned short* tbz = (unsigned short*)(smem + OFF_TBZ);
    unsigned short* hws = (unsigned short*)(smem + OFF_HWS);
    char* girz = smem + OFF_GI_RZ;
    char* gin  = smem + OFF_GI_N;
    float* prm1 = (float*)(smem + OFF_PRM1);
    float* prm2 = (float*)(smem + OFF_PRM2);
    float* prm3 = (float*)(smem + OFF_PRM3);
    float* prmN = (float*)(smem + OFF_PRMN);

    const int l   = threadIdx.x;     // 0..63
    const int lo  = l & 15;
    const int hi  = l >> 4;
    const int row0 = blockIdx.x * RPW;
    const size_t lane8 = (size_t)l * 8;

    // ---- param prep (folded BN constants into LDS) ----
    for (int c = l; c < H; c += 64) {
        float s1 = ld1<F32>(g1, c) * rsqrtf(ld1<F32>(v1, c) + 1e-5f);
        float t1 = ld1<F32>(be1, c) - ld1<F32>(m1, c) * s1 + ld1<F32>(blin, c) * s1;
        prm1[2*c] = s1; prm1[2*c+1] = t1;
        float s2 = ld1<F32>(g2, c) * rsqrtf(ld1<F32>(v2, c) + 1e-5f);
        prm2[2*c] = s2; prm2[2*c+1] = ld1<F32>(be2, c) - ld1<F32>(m2, c) * s2;
        float s3 = ld1<F32>(g3, c) * rsqrtf(ld1<F32>(v3, c) + 1e-5f);
        prm3[2*c] = s3;
        prm3[2*c+1] = (ld1<F32>(bc, c) - ld1<F32>(m3, c)) * s3 + ld1<F32>(be3, c);
        prmN[c] = ld1<F32>(bhh, 2 * H + c);
    }
    const float a1v = ld1<F32>(a1, 0), a2v = ld1<F32>(a2, 0), a3v = ld1<F32>(a3, 0);
    float bmu8[8];
    #pragma unroll
    for (int ot = 0; ot < 2; ++ot)
        #pragma unroll
        for (int r = 0; r < 4; ++r)
            bmu8[ot*4 + r] = ld1<F32>(bmu, ot*16 + 4*hi + r);

    // ---- stage hw slab (32 rows x 640) to LDS as bf16 ----
    {
        constexpr int NFR = RPW * F / 8;     // 2560 8-elem groups
        for (int i = l; i < NFR; i += 64) {
            int r = i / (F/8), c = (i % (F/8)) * 8;
            bf16x8 v = g8<F32>(hw, (size_t)(row0 + r) * F + c);
            *reinterpret_cast<bf16x8*>(hws + r * LDWS + c) = v;
        }
    }
    LGKM0();   // params + slab visible (intra-wave)

    // ---- Phase 1: x = prelu(bn1(rows @ Wlin^T)) -> tbh (D-layout) ----
    bf16x8 xB[2][8];
    {
        #pragma unroll 1
        for (int pass = 0; pass < 2; ++pass) {
            f32x4 acc[8][2] = {};
            #pragma unroll 2
            for (int kf = 0; kf < F/32; ++kf) {
                bf16x8 b0 = *reinterpret_cast<const bf16x8*>(hws + lo * LDWS + kf*32 + hi*8);
                bf16x8 b1 = *reinterpret_cast<const bf16x8*>(hws + (16 + lo) * LDWS + kf*32 + hi*8);
                #pragma unroll
                for (int o = 0; o < 8; ++o) {
                    const int ot = pass*8 + o, w = ot >> 1, j = ot & 1;
                    bf16x8 a = pk8(WLIN_E + ((size_t)(w*20 + kf)*2 + j)*512 + lane8);
                    acc[o][0] = MFMA16(a, b0, acc[o][0]);
                    acc[o][1] = MFMA16(a, b1, acc[o][1]);
                }
            }
            #pragma unroll
            for (int o = 0; o < 8; ++o) {
                const int ot = pass*8 + o, c0 = ot*16 + 4*hi;
                f32x4n p01 = *reinterpret_cast<const f32x4n*>(prm1 + 2*c0);
                f32x4n p23 = *reinterpret_cast<const f32x4n*>(prm1 + 2*c0 + 4);
                #pragma unroll
                for (int rg = 0; rg < 2; ++rg) {
                    u16x4 xq;
                    #pragma unroll
                    for (int r = 0; r < 4; ++r) {
                        float s = (r < 2) ? p01[2*r]   : p23[2*(r-2)];
                        float t = (r < 2) ? p01[2*r+1] : p23[2*(r-2)+1];
                        float v = acc[o][rg][r] * s + t;
                        v = (v >= 0.0f) ? v : a1v * v;
                        xq[r] = f2bs(v);
                    }
                    *reinterpret_cast<u16x4*>(tbh + (rg*16 + lo) * LDT + c0) = xq;
                }
            }
        }
        LGKM0();
        #pragma unroll
        for (int rg = 0; rg < 2; ++rg)
            #pragma unroll
            for (int f = 0; f < 8; ++f)
                xB[rg][f] = *reinterpret_cast<const bf16x8*>(tbh + (rg*16 + lo) * LDT + f*32 + hi*8);
    }

    // ---- Phase 2: gi = x @ Wih^T + biases -> gi LDS (D-layout) ----
    {
        #pragma unroll 2
        for (int ct = 0; ct < 16; ++ct) {
            const int w = ct >> 1, j = ct & 1, c0 = ct*16 + 4*hi;
            f32x4 acc[3][2] = {};
            #pragma unroll
            for (int kk = 0; kk < 8; ++kk) {
                bf16x8 a0 = pk8(WIH_E + ((size_t)((w*3+0)*8 + kk)*2 + j)*512 + lane8);
                bf16x8 a1 = pk8(WIH_E + ((size_t)((w*3+1)*8 + kk)*2 + j)*512 + lane8);
                bf16x8 a2 = pk8(WIH_E + ((size_t)((w*3+2)*8 + kk)*2 + j)*512 + lane8);
                acc[0][0] = MFMA16(a0, xB[0][kk], acc[0][0]);
                acc[0][1] = MFMA16(a0, xB[1][kk], acc[0][1]);
                acc[1][0] = MFMA16(a1, xB[0][kk], acc[1][0]);
                acc[1][1] = MFMA16(a1, xB[1][kk], acc[1][1]);
                acc[2][0] = MFMA16(a2, xB[0][kk], acc[2][0]);
                acc[2][1] = MFMA16(a2, xB[1][kk], acc[2][1]);
            }
            float br[4], bz[4], bn[4];
            #pragma unroll
            for (int r = 0; r < 4; ++r) {
                br[r] = ld1<F32>(bih, 0*H + c0 + r) + ld1<F32>(bhh, 0*H + c0 + r);
                bz[r] = ld1<F32>(bih, 1*H + c0 + r) + ld1<F32>(bhh, 1*H + c0 + r);
                bn[r] = ld1<F32>(bih, 2*H + c0 + r);
            }
            #pragma unroll
            for (int rg = 0; rg < 2; ++rg) {
                u32x4 rz; f32x4n nv;
                #pragma unroll
                for (int r = 0; r < 4; ++r) {
                    rz[r] = pack2(acc[0][rg][r] + br[r], acc[1][rg][r] + bz[r]);
                    nv[r] = acc[2][rg][r] + bn[r];
                }
                *reinterpret_cast<u32x4*>(girz + ((size_t)(rg*16 + ct)*64 + l)*16) = rz;
                *reinterpret_cast<f32x4n*>(gin + ((size_t)(rg*16 + ct)*64 + l)*16) = nv;
            }
        }
        LGKM0();
    }

    // ---- GRU loop: zero barriers, all phases in-wave ----
    bf16x8 hB[2][8] = {};
    #pragma unroll 1
    for (int t = 0; t < LSTEPS; ++t) {
        // --- gh + gates -> tbh (h), tby (y)
        #pragma unroll 2
        for (int ct = 0; ct < 16; ++ct) {
            const int w = ct >> 1, j = ct & 1, c0 = ct*16 + 4*hi;
            f32x4 acc[3][2] = {};
            if (t > 0) {
                #pragma unroll
                for (int kk = 0; kk < 8; ++kk) {
                    bf16x8 a0 = pk8(WHH_E + ((size_t)((w*3+0)*8 + kk)*2 + j)*512 + lane8);
                    bf16x8 a1 = pk8(WHH_E + ((size_t)((w*3+1)*8 + kk)*2 + j)*512 + lane8);
                    bf16x8 a2 = pk8(WHH_E + ((size_t)((w*3+2)*8 + kk)*2 + j)*512 + lane8);
                    acc[0][0] = MFMA16(a0, hB[0][kk], acc[0][0]);
                    acc[0][1] = MFMA16(a0, hB[1][kk], acc[0][1]);
                    acc[1][0] = MFMA16(a1, hB[0][kk], acc[1][0]);
                    acc[1][1] = MFMA16(a1, hB[1][kk], acc[1][1]);
                    acc[2][0] = MFMA16(a2, hB[0][kk], acc[2][0]);
                    acc[2][1] = MFMA16(a2, hB[1][kk], acc[2][1]);
                }
            }
            u32x4 rz0 = *reinterpret_cast<const u32x4*>(girz + ((size_t)(0*16 + ct)*64 + l)*16);
            u32x4 rz1 = *reinterpret_cast<const u32x4*>(girz + ((size_t)(1*16 + ct)*64 + l)*16);
            f32x4n n0 = *reinterpret_cast<const f32x4n*>(gin + ((size_t)(0*16 + ct)*64 + l)*16);
            f32x4n n1 = *reinterpret_cast<const f32x4n*>(gin + ((size_t)(1*16 + ct)*64 + l)*16);
            f32x4n bh4 = *reinterpret_cast<const f32x4n*>(prmN + c0);
            f32x4n p01 = *reinterpret_cast<const f32x4n*>(prm2 + 2*c0);
            f32x4n p23 = *reinterpret_cast<const f32x4n*>(prm2 + 2*c0 + 4);
            u16x4 ho0 = {}, ho1 = {};
            if (t > 0) {
                ho0 = *reinterpret_cast<const u16x4*>(tbh + lo * LDT + c0);
                ho1 = *reinterpret_cast<const u16x4*>(tbh + (16 + lo) * LDT + c0);
            }
            #pragma unroll
            for (int rg = 0; rg < 2; ++rg) {
                const u32x4  rz = rg ? rz1 : rz0;
                const f32x4n nn = rg ? n1  : n0;
                const u16x4  ho = rg ? ho1 : ho0;
                u16x4 hq, yq;
                #pragma unroll
                for (int r = 0; r < 4; ++r) {
                    float rr = sigm(bfu((unsigned short)(rz[r] & 0xffffu)) + acc[0][rg][r]);
                    float zz = sigm(bfu((unsigned short)(rz[r] >> 16)) + acc[1][rg][r]);
                    float nin = nn[r] + rr * (acc[2][rg][r] + bh4[r]);
                    float nv = 2.0f * sigm(2.0f * nin) - 1.0f;   // tanh
                    float hold = (t > 0) ? bfu(ho[r]) : 0.0f;
                    float hh = (1.0f - zz) * nv + zz * hold;
                    hq[r] = f2bs(hh);
                    float s2 = (r < 2) ? p01[2*r]   : p23[2*(r-2)];
                    float t2 = (r < 2) ? p01[2*r+1] : p23[2*(r-2)+1];
                    float y = bfu(hq[r]) * s2 + t2;
                    y = (y >= 0.0f) ? y : a2v * y;
                    yq[r] = f2bs(y);
                }
                *reinterpret_cast<u16x4*>(tbh + (rg*16 + lo) * LDT + c0) = hq;
                *reinterpret_cast<u16x4*>(tby + (rg*16 + lo) * LDT + c0) = yq;
            }
        }
        LGKM0();   // h/y writes complete (intra-wave, vmcnt untouched)

        bf16x8 yB[2][8];
        #pragma unroll
        for (int rg = 0; rg < 2; ++rg)
            #pragma unroll
            for (int f = 0; f < 8; ++f) {
                hB[rg][f] = *reinterpret_cast<const bf16x8*>(tbh + (rg*16 + lo) * LDT + f*32 + hi*8);
                yB[rg][f] = *reinterpret_cast<const bf16x8*>(tby + (rg*16 + lo) * LDT + f*32 + hi*8);
            }

        // --- Wc: z = prelu(bn3(y @ Wc^T)) -> tbz
        #pragma unroll 2
        for (int ot = 0; ot < 16; ++ot) {
            const int w = ot >> 1, j = ot & 1, c0 = ot*16 + 4*hi;
            f32x4 acc2[2] = {};
            #pragma unroll
            for (int kk = 0; kk < 8; ++kk) {
                bf16x8 a = pk8(WC_E + ((size_t)(w*8 + kk)*2 + j)*512 + lane8);
                acc2[0] = MFMA16(a, yB[0][kk], acc2[0]);
                acc2[1] = MFMA16(a, yB[1][kk], acc2[1]);
            }
            f32x4n p01 = *reinterpret_cast<const f32x4n*>(prm3 + 2*c0);
            f32x4n p23 = *reinterpret_cast<const f32x4n*>(prm3 + 2*c0 + 4);
            #pragma unroll
            for (int rg = 0; rg < 2; ++rg) {
                u16x4 zq;
                #pragma unroll
                for (int r = 0; r < 4; ++r) {
                    float s = (r < 2) ? p01[2*r]   : p23[2*(r-2)];
                    float tt = (r < 2) ? p01[2*r+1] : p23[2*(r-2)+1];
                    float z = acc2[rg][r] * s + tt;
                    z = (z >= 0.0f) ? z : a3v * z;
                    zq[r] = f2bs(z);
                }
                *reinterpret_cast<u16x4*>(tbz + (rg*16 + lo) * LDT + c0) = zq;
            }
        }
        LGKM0();

        bf16x8 zB[2][8];
        #pragma unroll
        for (int rg = 0; rg < 2; ++rg)
            #pragma unroll
            for (int f = 0; f < 8; ++f)
                zB[rg][f] = *reinterpret_cast<const bf16x8*>(tbz + (rg*16 + lo) * LDT + f*32 + hi*8);

        // --- Wmu: out(t) = z @ Wmu^T + bmu
        #pragma unroll
        for (int ot = 0; ot < 2; ++ot) {
            f32x4 acc3[2] = {};
            #pragma unroll
            for (int kk = 0; kk < 8; ++kk) {
                bf16x8 a = pk8(WMU_E + (size_t)(ot*8 + kk)*512 + lane8);
                acc3[0] = MFMA16(a, zB[0][kk], acc3[0]);
                acc3[1] = MFMA16(a, zB[1][kk], acc3[1]);
            }
            #pragma unroll
            for (int rg = 0; rg < 2; ++rg) {
                const size_t oi = (size_t)(row0 + rg*16 + lo) * (LSTEPS * CO)
                                + (size_t)t * CO + ot*16 + 4*hi;
                if constexpr (F32) {
                    f32x4n v;
                    #pragma unroll
                    for (int r = 0; r < 4; ++r) v[r] = acc3[rg][r] + bmu8[ot*4 + r];
                    *reinterpret_cast<f32x4n*>((float*)out + oi) = v;
                } else {
                    u16x4 v;
                    #pragma unroll
                    for (int r = 0; r < 4; ++r) v[r] = f2bs(acc3[rg][r] + bmu8[ot*4 + r]);
                    *reinterpret_cast<u16x4*>((unsigned short*)out + oi) = v;
                }
            }
        }
    }
}

__global__ __launch_bounds__(64, 1) void comm_wave(
    const void* hw, const void* blin,
    const void* g1, const void* be1, const void* m1, const void* v1, const void* a1,
    const void* bih, const void* bhh,
    const void* g2, const void* be2, const void* m2, const void* v2, const void* a2,
    const void* bc,
    const void* g3, const void* be3, const void* m3, const void* v3, const void* a3,
    const void* bmu,
    void* out)
{
    __shared__ __align__(16) char smem[SMEM_SZ];
    if (g_flag) {
        wave_pipe<true >(hw, blin, g1, be1, m1, v1, a1, bih, bhh,
                         g2, be2, m2, v2, a2, bc, g3, be3, m3, v3, a3, bmu,
                         out, smem);
    } else {
        wave_pipe<false>(hw, blin, g1, be1, m1, v1, a1, bih, bhh,
                         g2, be2, m2, v2, a2, bc, g3, be3, m3, v3, a3, bmu,
                         out, smem);
    }
}

extern "C" void kernel_launch(void* const* d_in, const int* in_sizes, int n_in,
                              void* d_out, int out_size, void* d_ws, size_t ws_size,
                              hipStream_t stream) {
    (void)in_sizes; (void)n_in; (void)out_size; (void)d_ws; (void)ws_size;
    detect_dtype<<<dim3(1), dim3(1), 0, stream>>>(d_in[6]);
    prepack<<<dim3(308), dim3(256), 0, stream>>>(
        d_in[1], d_in[8], d_in[9], d_in[17], d_in[24]);
    comm_wave<<<dim3(256), dim3(64), 0, stream>>>(
        d_in[0], d_in[2],
        d_in[3], d_in[4], d_in[5], d_in[6], d_in[7],
        d_in[10], d_in[11],
        d_in[12], d_in[13], d_in[14], d_in[15], d_in[16],
        d_in[18],
        d_in[19], d_in[20], d_in[21], d_in[22], d_in[23],
        d_in[25],
        d_out);
}

// Round 8
// 439.271 us; speedup vs baseline: 2.5892x; 2.5892x over previous
//
#include <hip/hip_runtime.h>
#include <hip/hip_bf16.h>

// Fused Comm_OUT pipeline, batch-row-parallel (GRU recurrence is per-row).
// Round-14: INDEPENDENT BARRIER DOMAINS. Synthesis of r0-r7: per-step
// issue work ~5k cyc but measured 4-10x -> stall-bound; r1 (16 waves,
// ONE domain) flat because a domain's waves convoy (all drain at the
// same barrier simultaneously); r7 (1 wave, 0 barriers) 2.5x worse
// (gate VALU serialized on one SIMD). Untested lever: 2 INDEPENDENT
// blocks/CU whose barrier drains interleave - while block A waits at
// its barrier, block B issues. r6 structure with BM=16, 512 blocks:
// LDS 50.7KB/block, VGPR=128 -> exactly 2 resident blocks (16 waves/CU).
// Everything else r6-verbatim: 1 barrier/step, peeled steady body,
// 2-deep kk prefetch in gh, Wc/Wmu software-pipelined behind recurrence.
// 512 blocks x 512 threads (8 waves x 32 cols), BM=16.
// Runtime dtype detection (inputs fp32 or bf16) via g_flag.

typedef __attribute__((ext_vector_type(8))) short bf16x8;   // 8 x bf16 (4 VGPRs)
typedef __attribute__((ext_vector_type(4))) float f32x4;    // MFMA accumulator

#define MFMA16(a, b, c) __builtin_amdgcn_mfma_f32_16x16x32_bf16((a), (b), (c), 0, 0, 0)

constexpr int F   = 640;
constexpr int H   = 256;
constexpr int LSTEPS = 20;
constexpr int CO  = 32;
constexpr int LDP = 264;   // padded bf16 row stride (16B-aligned rows)
constexpr int BM  = 16;    // rows per block (r14: halved for 2 blocks/CU)

// packed-weight element offsets inside g_wpk (layout unchanged from r7)
constexpr size_t WHH_E  = 0;                    // 8cg*3g*8kk*2j*64lane*8 = 196608
constexpr size_t WIH_E  = 196608;               // 196608
constexpr size_t WC_E   = 393216;               // 8cg*8kk*2j*64*8       = 65536
constexpr size_t WMU_E  = 458752;               // 2w*8kk*64*8           = 8192
constexpr size_t WLIN_E = 466944;               // 8cg*20kk*2j*64*8      = 163840
constexpr size_t PK_ELEMS = 630784;

__device__ __align__(16) unsigned short g_wpk[PK_ELEMS];
__device__ int g_flag;     // 1 = inputs are fp32

__device__ __forceinline__ float bf2f(__hip_bfloat16 x) { return __bfloat162float(x); }
__device__ __forceinline__ float bfu(unsigned short s) {
    __hip_bfloat16 h = *reinterpret_cast<__hip_bfloat16*>(&s);
    return __bfloat162float(h);
}
__device__ __forceinline__ unsigned short f2bs(float f) {
    __hip_bfloat16 h = __float2bfloat16(f);
    return *reinterpret_cast<unsigned short*>(&h);
}
__device__ __forceinline__ bf16x8 lds8(const unsigned short* p) {
    return *reinterpret_cast<const bf16x8*>(p);
}
__device__ __forceinline__ bf16x8 pk8(size_t eoff) {
    return *reinterpret_cast<const bf16x8*>(g_wpk + eoff);
}
__device__ __forceinline__ float sigm(float x) {
    return 1.0f / (1.0f + __expf(-x));
}
__device__ __forceinline__ unsigned pack2(float lo, float hi) {
    return (unsigned)f2bs(lo) | ((unsigned)f2bs(hi) << 16);
}

template<bool F32>
__device__ __forceinline__ bf16x8 g8(const void* base, size_t off) {
    if constexpr (!F32) {
        return *reinterpret_cast<const bf16x8*>((const __hip_bfloat16*)base + off);
    } else {
        const float* f = (const float*)base + off;
        float4 lo = *reinterpret_cast<const float4*>(f);
        float4 hi = *reinterpret_cast<const float4*>(f + 4);
        bf16x8 r;
        r[0] = (short)f2bs(lo.x); r[1] = (short)f2bs(lo.y);
        r[2] = (short)f2bs(lo.z); r[3] = (short)f2bs(lo.w);
        r[4] = (short)f2bs(hi.x); r[5] = (short)f2bs(hi.y);
        r[6] = (short)f2bs(hi.z); r[7] = (short)f2bs(hi.w);
        return r;
    }
}

template<bool F32>
__device__ __forceinline__ float ld1(const void* base, int i) {
    if constexpr (!F32) return bf2f(((const __hip_bfloat16*)base)[i]);
    else                return ((const float*)base)[i];
}

// ---------------- dtype detect: v1 (uniform[0.5,1.5]) ----------------
__global__ void detect_dtype(const void* v1) {
    const unsigned short* u = (const unsigned short*)v1;
    int f32 = 0;
    for (int i = 0; i < 8; ++i) {
        unsigned short s = u[i];
        __hip_bfloat16 h = *reinterpret_cast<__hip_bfloat16*>(&s);
        float v = __bfloat162float(h);
        if (!(v >= 0.25f && v <= 2.0f)) f32 = 1;
    }
    g_flag = f32;
}

// ---------------- weight pre-pack (fp32|bf16 -> bf16 fragment streams) ----------------
__device__ __forceinline__ unsigned short cvt1(const void* p, size_t i, bool f32) {
    if (f32) return f2bs(((const float*)p)[i]);
    return ((const unsigned short*)p)[i];
}

__global__ void prepack(const void* Wlin, const void* Wih, const void* Whh,
                        const void* Wc, const void* Wmu) {
    const bool f32 = (g_flag != 0);
    const int gid = blockIdx.x * 256 + threadIdx.x;
    const void* src;
    size_t dbase;
    int row, col0, ncols;
    if (gid < 24576) {                       // Whh [768,256]
        int idx = gid;
        int lane = idx & 63, j = (idx >> 6) & 1, kk = (idx >> 7) & 7;
        int t2 = idx >> 10, g = t2 % 3, w = t2 / 3;
        row = g * 256 + w * 32 + j * 16 + (lane & 15);
        col0 = kk * 32 + (lane >> 4) * 8;
        ncols = 256; src = Whh; dbase = WHH_E + (size_t)idx * 8;
    } else if (gid < 49152) {                // Wih [768,256]
        int idx = gid - 24576;
        int lane = idx & 63, j = (idx >> 6) & 1, kk = (idx >> 7) & 7;
        int t2 = idx >> 10, g = t2 % 3, w = t2 / 3;
        row = g * 256 + w * 32 + j * 16 + (lane & 15);
        col0 = kk * 32 + (lane >> 4) * 8;
        ncols = 256; src = Wih; dbase = WIH_E + (size_t)idx * 8;
    } else if (gid < 57344) {                // Wc [256,256]
        int idx = gid - 49152;
        int lane = idx & 63, j = (idx >> 6) & 1, kk = (idx >> 7) & 7, w = idx >> 10;
        row = w * 32 + j * 16 + (lane & 15);
        col0 = kk * 32 + (lane >> 4) * 8;
        ncols = 256; src = Wc; dbase = WC_E + (size_t)idx * 8;
    } else if (gid < 58368) {                // Wmu [32,256]
        int idx = gid - 57344;
        int lane = idx & 63, kk = (idx >> 6) & 7, w = idx >> 9;
        row = w * 16 + (lane & 15);
        col0 = kk * 32 + (lane >> 4) * 8;
        ncols = 256; src = Wmu; dbase = WMU_E + (size_t)idx * 8;
    } else if (gid < 78848) {                // Wlin [256,640]
        int idx = gid - 58368;
        int lane = idx & 63, j = (idx >> 6) & 1;
        int t1 = idx >> 7, kk = t1 % 20, w = t1 / 20;
        row = w * 32 + j * 16 + (lane & 15);
        col0 = kk * 32 + (lane >> 4) * 8;
        ncols = 640; src = Wlin; dbase = WLIN_E + (size_t)idx * 8;
    } else {
        return;
    }
    const size_t s0 = (size_t)row * ncols + col0;
    #pragma unroll
    for (int i = 0; i < 8; ++i) g_wpk[dbase + i] = cvt1(src, s0 + i, f32);
}

// ---------------- FAST PATH: BM=16, 512 threads, 8 waves, 1 barrier/step ----------------
template<bool F32>
__device__ __forceinline__ void fast_pipe(
    const void* hw, const void* blin,
    const void* g1, const void* be1, const void* m1, const void* v1, const void* a1,
    const void* bih, const void* bhh,
    const void* g2, const void* be2, const void* m2, const void* v2, const void* a2,
    const void* bc,
    const void* g3, const void* be3, const void* m3, const void* v3, const void* a3,
    const void* bmu,
    void* out,
    unsigned short (*hb)[BM * LDP],
    unsigned short (*yb)[BM * LDP],
    unsigned short (*zb)[BM * LDP])
{
    const int tid  = threadIdx.x;
    const int cg   = tid >> 6;        // wave = 32-col group, 0..7
    const int lane = tid & 63;
    const int m16  = lane & 15;
    const int q    = lane >> 4;
    const int row0 = blockIdx.x * BM;
    const int c0 = cg * 32 + m16;
    const int c1 = c0 + 16;
    const int cc2[2] = { c0, c1 };
    const size_t lane8 = (size_t)lane * 8;

    // persistent per-step params (folded)
    float s2v[2], t2v[2], s3v[2], t3f[2], bhhn[2];
    #pragma unroll
    for (int j = 0; j < 2; ++j) {
        const int cc = cc2[j];
        float s;
        s = ld1<F32>(g2, cc) * rsqrtf(ld1<F32>(v2, cc) + 1e-5f);
        s2v[j] = s; t2v[j] = ld1<F32>(be2, cc) - ld1<F32>(m2, cc) * s;
        s = ld1<F32>(g3, cc) * rsqrtf(ld1<F32>(v3, cc) + 1e-5f);
        s3v[j] = s;
        t3f[j] = (ld1<F32>(bc, cc) - ld1<F32>(m3, cc)) * s + ld1<F32>(be3, cc);
        bhhn[j] = ld1<F32>(bhh, 2 * H + cc);
    }
    const float a2v = ld1<F32>(a2, 0), a3v = ld1<F32>(a3, 0);

    // ---- Phase 1: x = prelu(bn1(rows @ Wlin^T + blin)) -> yb[0] ----
    {
        f32x4 xacc[2] = {};   // [j]
        #pragma unroll 5
        for (int kk = 0; kk < F / 32; ++kk) {
            bf16x8 fa0 = g8<F32>(hw, (size_t)(row0 + m16) * F + kk * 32 + q * 8);
            bf16x8 b0 = pk8(WLIN_E + (size_t)((cg * 20 + kk) * 2 + 0) * 512 + lane8);
            bf16x8 b1 = pk8(WLIN_E + (size_t)((cg * 20 + kk) * 2 + 1) * 512 + lane8);
            xacc[0] = MFMA16(fa0, b0, xacc[0]);
            xacc[1] = MFMA16(fa0, b1, xacc[1]);
        }
        #pragma unroll
        for (int j = 0; j < 2; ++j) {
            const int cc = cc2[j];
            float s = ld1<F32>(g1, cc) * rsqrtf(ld1<F32>(v1, cc) + 1e-5f);
            float t = ld1<F32>(be1, cc) - ld1<F32>(m1, cc) * s;
            float bl = ld1<F32>(blin, cc);
            float av = ld1<F32>(a1, 0);
            #pragma unroll
            for (int r = 0; r < 4; ++r) {
                float vv = (xacc[j][r] + bl) * s + t;
                vv = (vv >= 0.0f) ? vv : av * vv;
                yb[0][(q * 4 + r) * LDP + cc] = f2bs(vv);
            }
        }
    }
    __syncthreads();   // x visible in yb[0]

    // ---- Phase 2: gi = x @ Wih^T + biases; r/z packed bf16, n kept f32 ----
    unsigned girz[2][4];   // [j][r]: lo = r-gate, hi = z-gate pre-act
    f32x4 gin[2];          // [j]: n-gate pre-act
    {
        f32x4 ga[3][2] = {};
        const unsigned short* xa0 = yb[0] + m16 * LDP + q * 8;
        #pragma unroll
        for (int kk = 0; kk < 8; ++kk) {
            bf16x8 fa0 = lds8(xa0 + kk * 32);
            #pragma unroll
            for (int g = 0; g < 3; ++g) {
                bf16x8 b0 = pk8(WIH_E + (size_t)(((cg * 3 + g) * 8 + kk) * 2 + 0) * 512 + lane8);
                bf16x8 b1 = pk8(WIH_E + (size_t)(((cg * 3 + g) * 8 + kk) * 2 + 1) * 512 + lane8);
                ga[g][0] = MFMA16(fa0, b0, ga[g][0]);
                ga[g][1] = MFMA16(fa0, b1, ga[g][1]);
            }
        }
        #pragma unroll
        for (int j = 0; j < 2; ++j) {
            const float br = ld1<F32>(bih, 0 * H + cc2[j]) + ld1<F32>(bhh, 0 * H + cc2[j]);
            const float bz = ld1<F32>(bih, 1 * H + cc2[j]) + ld1<F32>(bhh, 1 * H + cc2[j]);
            const float bn = ld1<F32>(bih, 2 * H + cc2[j]);
            #pragma unroll
            for (int r = 0; r < 4; ++r)
                girz[j][r] = pack2(ga[0][j][r] + br, ga[1][j][r] + bz);
            #pragma unroll
            for (int r = 0; r < 4; ++r) gin[j][r] = ga[2][j][r] + bn;
        }
    }
    __syncthreads();   // protects yb[0] for reuse as y(0) at iter 0

    // ---- GRU loop state ----
    unsigned short hs[2][4];
    #pragma unroll
    for (int j = 0; j < 2; ++j)
        #pragma unroll
        for (int r = 0; r < 4; ++r) hs[j][r] = 0;   // bf16 +0.0

    const int nto = cg & 1;   // for cg<2: output col tile
    const float bmuv = (cg < 2) ? ld1<F32>(bmu, nto * 16 + m16) : 0.0f;

    // --- phase lambdas (inlined; straight-line in the steady body) ---
    auto do_wc = [&](int prv) {
        f32x4 w2[2] = {};
        const unsigned short* ya0 = yb[prv] + m16 * LDP + q * 8;
        #pragma unroll
        for (int kk = 0; kk < 8; ++kk) {
            bf16x8 fa0 = lds8(ya0 + kk * 32);
            bf16x8 b0 = pk8(WC_E + (size_t)((cg * 8 + kk) * 2 + 0) * 512 + lane8);
            bf16x8 b1 = pk8(WC_E + (size_t)((cg * 8 + kk) * 2 + 1) * 512 + lane8);
            w2[0] = MFMA16(fa0, b0, w2[0]);
            w2[1] = MFMA16(fa0, b1, w2[1]);
        }
        #pragma unroll
        for (int j = 0; j < 2; ++j)
            #pragma unroll
            for (int r = 0; r < 4; ++r) {
                float z0 = w2[j][r] * s3v[j] + t3f[j];
                z0 = (z0 >= 0.0f) ? z0 : a3v * z0;
                zb[prv][(q * 4 + r) * LDP + cc2[j]] = f2bs(z0);
            }
    };

    auto do_wmu = [&](int cur, int ts) {
        if (cg < 2) {
            const unsigned short* za = zb[cur] + m16 * LDP + q * 8;
            f32x4 o = {};
            #pragma unroll
            for (int kk = 0; kk < 8; ++kk) {
                bf16x8 a = lds8(za + kk * 32);
                bf16x8 b = pk8(WMU_E + (size_t)(nto * 8 + kk) * 512 + lane8);
                o = MFMA16(a, b, o);
            }
            #pragma unroll
            for (int r = 0; r < 4; ++r) {
                float vv = o[r] + bmuv;
                const size_t oi = (size_t)(row0 + q * 4 + r) * (LSTEPS * CO)
                                + ts * CO + nto * 16 + m16;
                if constexpr (F32) ((float*)out)[oi] = vv;
                else               ((__hip_bfloat16*)out)[oi] = __float2bfloat16(vv);
            }
        }
    };

    auto do_rec = [&](int cur, int prv, bool hasGh) {
        f32x4 gh[3][2] = {};
        if (hasGh) {
            const unsigned short* ha0 = hb[prv] + m16 * LDP + q * 8;
            // 2-deep kk prefetch of the 6 b-frags (static after full unroll)
            bf16x8 pre[2][6];
            #pragma unroll
            for (int kk = 0; kk < 2; ++kk)
                #pragma unroll
                for (int g = 0; g < 3; ++g)
                    #pragma unroll
                    for (int j = 0; j < 2; ++j)
                        pre[kk][g * 2 + j] =
                            pk8(WHH_E + (size_t)(((cg * 3 + g) * 8 + kk) * 2 + j) * 512 + lane8);
            #pragma unroll
            for (int kk = 0; kk < 8; ++kk) {
                bf16x8 b00 = pre[kk & 1][0];
                bf16x8 b01 = pre[kk & 1][1];
                bf16x8 b10 = pre[kk & 1][2];
                bf16x8 b11 = pre[kk & 1][3];
                bf16x8 b20 = pre[kk & 1][4];
                bf16x8 b21 = pre[kk & 1][5];
                if (kk < 6) {
                    #pragma unroll
                    for (int g = 0; g < 3; ++g)
                        #pragma unroll
                        for (int j = 0; j < 2; ++j)
                            pre[kk & 1][g * 2 + j] =
                                pk8(WHH_E + (size_t)(((cg * 3 + g) * 8 + (kk + 2)) * 2 + j) * 512 + lane8);
                }
                bf16x8 fa0 = lds8(ha0 + kk * 32);
                gh[0][0] = MFMA16(fa0, b00, gh[0][0]);
                gh[0][1] = MFMA16(fa0, b01, gh[0][1]);
                gh[1][0] = MFMA16(fa0, b10, gh[1][0]);
                gh[1][1] = MFMA16(fa0, b11, gh[1][1]);
                gh[2][0] = MFMA16(fa0, b20, gh[2][0]);
                gh[2][1] = MFMA16(fa0, b21, gh[2][1]);
            }
        }
        #pragma unroll
        for (int j = 0; j < 2; ++j)
            #pragma unroll
            for (int r = 0; r < 4; ++r) {
                unsigned u = girz[j][r];
                float rr = sigm(bfu((unsigned short)(u & 0xffffu)) + gh[0][j][r]);
                float zz = sigm(bfu((unsigned short)(u >> 16)) + gh[1][j][r]);
                float nin = gin[j][r] + rr * (gh[2][j][r] + bhhn[j]);
                float nn = 2.0f * sigm(2.0f * nin) - 1.0f;   // tanh
                float hh = (1.0f - zz) * nn + zz * bfu(hs[j][r]);
                unsigned short hv = f2bs(hh);
                hs[j][r] = hv;
                const int idx = (q * 4 + r) * LDP + cc2[j];
                hb[cur][idx] = hv;
                float y = bfu(hv) * s2v[j] + t2v[j];
                y = (y >= 0.0f) ? y : a2v * y;
                yb[cur][idx] = f2bs(y);
            }
    };

    // ---- peeled schedule: 1 barrier/step, Wc/Wmu pipelined behind ----
    // t=0: recurrence only (gh = 0)
    do_rec(0, 1, false);
    __syncthreads();
    // t=1: Wc on y(0); recurrence(1)
    do_wc(0);
    do_rec(1, 0, true);
    __syncthreads();
    // steady: t=2..LSTEPS-1, straight-line body
    #pragma unroll 1
    for (int t = 2; t < LSTEPS; ++t) {
        const int cur = t & 1, prv = cur ^ 1;
        do_wc(prv);
        do_wmu(cur, t - 2);
        do_rec(cur, prv, true);
        __syncthreads();
    }
    // t=LSTEPS: Wc on y(19); Wmu -> out(18)
    {
        const int cur = LSTEPS & 1, prv = cur ^ 1;
        do_wc(prv);
        do_wmu(cur, LSTEPS - 2);
        __syncthreads();
    }
    // t=LSTEPS+1: Wmu -> out(19)
    {
        const int cur = (LSTEPS + 1) & 1;
        do_wmu(cur, LSTEPS - 1);
    }
}

__global__ __launch_bounds__(512, 2) void comm_fast(
    const void* hw, const void* blin,
    const void* g1, const void* be1, const void* m1, const void* v1, const void* a1,
    const void* bih, const void* bhh,
    const void* g2, const void* be2, const void* m2, const void* v2, const void* a2,
    const void* bc,
    const void* g3, const void* be3, const void* m3, const void* v3, const void* a3,
    const void* bmu,
    void* out)
{
    __shared__ __align__(16) unsigned short hb[2][BM * LDP];
    __shared__ __align__(16) unsigned short yb[2][BM * LDP];
    __shared__ __align__(16) unsigned short zb[2][BM * LDP];
    if (g_flag) {
        fast_pipe<true >(hw, blin, g1, be1, m1, v1, a1, bih, bhh,
                         g2, be2, m2, v2, a2, bc, g3, be3, m3, v3, a3, bmu,
                         out, hb, yb, zb);
    } else {
        fast_pipe<false>(hw, blin, g1, be1, m1, v1, a1, bih, bhh,
                         g2, be2, m2, v2, a2, bc, g3, be3, m3, v3, a3, bmu,
                         out, hb, yb, zb);
    }
}

extern "C" void kernel_launch(void* const* d_in, const int* in_sizes, int n_in,
                              void* d_out, int out_size, void* d_ws, size_t ws_size,
                              hipStream_t stream) {
    (void)in_sizes; (void)n_in; (void)out_size; (void)d_ws; (void)ws_size;
    detect_dtype<<<dim3(1), dim3(1), 0, stream>>>(d_in[6]);
    prepack<<<dim3(308), dim3(256), 0, stream>>>(
        d_in[1], d_in[8], d_in[9], d_in[17], d_in[24]);
    comm_fast<<<dim3(512), dim3(512), 0, stream>>>(
        d_in[0], d_in[2],
        d_in[3], d_in[4], d_in[5], d_in[6], d_in[7],
        d_in[10], d_in[11],
        d_in[12], d_in[13], d_in[14], d_in[15], d_in[16],
        d_in[18],
        d_in[19], d_in[20], d_in[21], d_in[22], d_in[23],
        d_in[25],
        d_out);
}